// Round 14
// baseline (120.790 us; speedup 1.0000x reference)
//
#include <hip/hip_runtime.h>

#define B_ 2
#define T_ 8
#define Z_ 20
#define Y_ 64
#define X_ 64
#define C_ 2
#define F1_ 32
#define F_ 32

constexpr int NPTS = B_*T_*Z_*Y_*X_;   // 1,310,720
constexpr int ZYX  = Z_*Y_*X_;         // 81,920

constexpr int HALO2   = 3*3*34;        // 306 uint2 per slice per wave
constexpr int NKB     = 11;            // K = 352 (324 real + pad)
constexpr int K_REAL  = 324;

using bf8   = __attribute__((ext_vector_type(8))) short;
using f32x4 = __attribute__((ext_vector_type(4))) float;

__device__ inline unsigned short f2bf(float x) {   // RNE float->bf16
    unsigned u = __builtin_bit_cast(unsigned, x);
    return (unsigned short)((u + 0x7fff + ((u >> 16) & 1)) >> 16);
}
__device__ inline unsigned pk(float a, float b) {  // pack 2 bf16 into dword
    return (unsigned)f2bf(a) | ((unsigned)f2bf(b) << 16);
}

// ---------------------------------------------------------------------------
// Weight projection (verified, unchanged). Outputs fp32 projected weights:
// psr/psi[(tap*2+cin)*32 + f1], ptr_/pti[(kt*32+f1)*32 + f].
// ---------------------------------------------------------------------------
__global__ __launch_bounds__(64) void project_kernel(
    const float* __restrict__ wxr, const float* __restrict__ wxi,
    const float* __restrict__ wtr, const float* __restrict__ wti,
    float* __restrict__ psr, float* __restrict__ psi,
    float* __restrict__ otr, float* __restrict__ oti)
{
    const int bid  = blockIdx.x;
    const int lane = threadIdx.x;

    if (bid < F1_) {
        const int f = bid;
        float er = 0.f, ei = 0.f;
        if (lane < 54) { er = wxr[lane*F1_ + f]; ei = wxi[lane*F1_ + f]; }
        float sr = er, si = ei;
        #pragma unroll
        for (int o = 32; o >= 1; o >>= 1) { sr += __shfl_xor(sr, o); si += __shfl_xor(si, o); }
        const float mr = sr * (1.f/54.f), mi = si * (1.f/54.f);
        const float dr = er - mr, di = ei - mi;
        float sq = (lane < 54) ? (dr*dr + di*di) : 0.f;
        #pragma unroll
        for (int o = 32; o >= 1; o >>= 1) sq += __shfl_xor(sq, o);
        const float s = 1.f / fmaxf(sqrtf(sq), 1.f);
        if (lane < 54) { psr[lane*F1_ + f] = dr*s; psi[lane*F1_ + f] = di*s; }
    } else {
        const int f = bid - F1_;
        float er[2], ei[2];
        float sq = 0.f;
        #pragma unroll
        for (int k = 0; k < 2; ++k) {
            const int e = lane + k*64;
            if (e < 96) { er[k] = wtr[e*F_ + f]; ei[k] = wti[e*F_ + f]; sq += er[k]*er[k] + ei[k]*ei[k]; }
            else        { er[k] = 0.f;  ei[k] = 0.f; }
        }
        #pragma unroll
        for (int o = 32; o >= 1; o >>= 1) sq += __shfl_xor(sq, o);
        const float s = 1.f / fmaxf(sqrtf(sq), 1.f);
        #pragma unroll
        for (int k = 0; k < 2; ++k) {
            const int e = lane + k*64;
            if (e < 96) { otr[e*F_ + f] = er[k]*s; oti[e*F_ + f] = ei[k]*s; }
        }
    }
}

// ---------------------------------------------------------------------------
// Combined-weight pack: W4[K4][n], K4 = tap4*4 + q, tap4 = kt*27+tap in
// [0,81), q = cp*2+cin; n<32 -> yr[f=n], n>=32 -> yi[f=n-32].
// W4 = f1-contraction of (spatial complex weight) x (temporal complex weight):
//   cr = sum_f1 wsr*wtr - wsi*wti ; ci = sum_f1 wsr*wti + wsi*wtr
//   W4[n<32] = cp ? -ci : cr ;  W4[n>=32] = cp ? cr : ci.
// Emitted directly in MFMA B-fragment order (layout identical to verified
// packs): wc[((ct*11+kb)*64 + l)*8 + j] = W4[kb*32+(l>>4)*8+j][ct*16+(l&15)].
// ---------------------------------------------------------------------------
__global__ __launch_bounds__(256) void pack_comb_kernel(
    const float* __restrict__ psr, const float* __restrict__ psi,
    const float* __restrict__ ptr_, const float* __restrict__ pti,
    unsigned short* __restrict__ wc)
{
    for (int o = blockIdx.x*512 + threadIdx.x; o < blockIdx.x*512 + 512; o += 256) {
        const int j  = o & 7;
        const int l  = (o >> 3) & 63;
        const int g  = o >> 9;           // ct*11 + kb
        const int kb = g % NKB, ct = g / NKB;
        const int k  = kb*32 + (l >> 4)*8 + j;
        const int n  = ct*16 + (l & 15);
        float v = 0.f;
        if (k < K_REAL) {
            const int tap4 = k >> 2, q = k & 3, cin = q & 1, cp = q >> 1;
            const int kt = tap4 / 27, tap = tap4 % 27;
            const int f  = n & 31;
            float cr = 0.f, ci = 0.f;
            const float* wsr = psr + (tap*2 + cin)*F1_;
            const float* wsi = psi + (tap*2 + cin)*F1_;
            #pragma unroll 8
            for (int f1 = 0; f1 < F1_; ++f1) {
                const float ar = wsr[f1],                    ai = wsi[f1];
                const float br = ptr_[(kt*F1_ + f1)*F_ + f], bi = pti[(kt*F1_ + f1)*F_ + f];
                cr += ar*br - ai*bi;
                ci += ar*bi + ai*br;
            }
            v = (n < 32) ? (cp ? -ci : cr) : (cp ? cr : ci);
        }
        wc[o] = f2bf(v);
    }
}

// ---------------------------------------------------------------------------
// Repack input to bf16: xb[p] = uint2{ r0|r1<<16, i0|i1<<16 }. Unchanged.
// ---------------------------------------------------------------------------
__global__ __launch_bounds__(256) void repack_kernel(
    const float* __restrict__ xr, const float* __restrict__ xi,
    uint2* __restrict__ xb)
{
    const int p = blockIdx.x*256 + threadIdx.x;
    const float2 vr = *reinterpret_cast<const float2*>(xr + (size_t)p*2);
    const float2 vi = *reinterpret_cast<const float2*>(xi + (size_t)p*2);
    uint2 v;
    v.x = (unsigned)f2bf(vr.x) | ((unsigned)f2bf(vr.y) << 16);
    v.y = (unsigned)f2bf(vi.x) | ((unsigned)f2bf(vi.y) << 16);
    xb[p] = v;
}

// ---------------------------------------------------------------------------
// Fused SINGLE-GEMM kernel: y(t) computed directly from input slices
// {t-1,t,t+1} (3-slot sliding LDS slab, one new slice staged per t) with the
// combined 352x64 weight held in 176 VGPRs. No intermediate, no ring, no
// bf16 conversion of s. Dual x-tile per wave (r10 mapping). A-fragment build,
// MFMA operand convention, and store epilogue byte-inherited from the
// verified kernels.
// ---------------------------------------------------------------------------
__global__ __launch_bounds__(256, 2) void fused_kernel(
    const uint2* __restrict__ xb,
    const unsigned short* __restrict__ wc,
    float* __restrict__ yr, float* __restrict__ yi)
{
    __shared__ uint2 slab[4][3*HALO2];       // 29.4 KB

    const int tid  = threadIdx.x;
    const int lane = tid & 63;
    const int wid  = tid >> 6;
    const int lx   = lane & 15;
    const int lg   = lane >> 4;

    const int bq    = blockIdx.x;        // b*Z*32 + z*32 + ypair
    const int ypair = bq & 31;           // Y/2 = 32
    const int z     = (bq >> 5) % Z_;
    const int b     = bq / (32*Z_);
    const int y     = ypair*2 + (wid >> 1);
    const int x0    = (wid & 1) * 32;

    // ---- combined weight fragments: 44 x 16B (176 VGPR) ----
    bf8 wcf[4][NKB];
    const bf8* w8 = reinterpret_cast<const bf8*>(wc);
    #pragma unroll
    for (int ct = 0; ct < 4; ++ct)
        #pragma unroll
        for (int kb = 0; kb < NKB; ++kb)
            wcf[ct][kb] = w8[(ct*NKB + kb)*64 + lane];

    // ---- staging offsets: 5 slots covering 306 halo points (per slice) ----
    int xoff[5];
    #pragma unroll
    for (int i = 0; i < 5; ++i) {
        int it = lane + i*64; if (it >= HALO2) it = HALO2-1;  // dup, write-guarded
        const int iz = it / 102;         // 102 = 3y*34x
        const int iy = (it / 34) % 3;
        const int ix = it % 34;
        int zz = z + iz - 1;  zz = zz < 0 ? 0 : (zz >= Z_ ? Z_-1 : zz);
        int yy = y + iy - 1;  yy = yy < 0 ? 0 : (yy >= Y_ ? Y_-1 : yy);
        int xx = x0 + ix - 1; xx = xx < 0 ? 0 : (xx >= X_ ? X_-1 : xx);
        xoff[i] = (zz*Y_ + yy)*X_ + xx;
    }

    // ---- per-lane slab offsets (incl. kt-slot base), packed 2x16b ----
    // element i = kb*2+s: tap4 = kb*8 + lg*2 + s (clamped; K4>=324 has W=0)
    unsigned koff2[NKB];
    #pragma unroll
    for (int kb = 0; kb < NKB; ++kb) {
        unsigned pair = 0;
        #pragma unroll
        for (int s = 0; s < 2; ++s) {
            int t4 = kb*8 + lg*2 + s; if (t4 > 80) t4 = 80;
            const int kt = t4/27, tap = t4 - kt*27;
            const int dz = tap/9, dyx = tap - dz*9, dy = dyx/3, dx = dyx - dy*3;
            const unsigned off = kt*HALO2 + (dz*3 + dy)*34 + dx + lx;
            pair |= off << (16*s);
        }
        koff2[kb] = pair;
    }

    uint2* sl = slab[wid];
    const size_t orow = (((size_t)b*T_)*Z_ + z)*(size_t)(Y_*X_) + (size_t)y*X_ + x0 + lx;

    uint2 stmp[5];                               // in-flight slice loads

    auto STAGE_ISSUE = [&](int tau) {            // coalesced, clamped slice
        const int tc = tau < 0 ? 0 : (tau >= T_ ? T_-1 : tau);
        const uint2* xt = xb + (size_t)(b*T_ + tc)*ZYX;
        #pragma unroll
        for (int i = 0; i < 4; ++i) stmp[i] = xt[xoff[i]];
        if (lane < HALO2 - 256) stmp[4] = xt[xoff[4]];
    };
    auto STAGE_WRITE = [&](int slot) {
        uint2* s = sl + slot*HALO2;
        #pragma unroll
        for (int i = 0; i < 4; ++i) s[lane + i*64] = stmp[i];
        if (lane < HALO2 - 256) s[lane + 256] = stmp[4];
    };

    // single GEMM for one tile: 11 kb x 4 ct MFMAs straight from the slab
    auto COMPUTE = [&](int rot, int t, int xadd, int tsel) {
        f32x4 acc[4];
        #pragma unroll
        for (int ct = 0; ct < 4; ++ct) acc[ct] = (f32x4){0.f,0.f,0.f,0.f};
        __builtin_amdgcn_s_setprio(1);
        #pragma unroll
        for (int kb = 0; kb < NKB; ++kb) {
            int oa = (int)(koff2[kb] & 0xffffu) + rot; if (oa >= 3*HALO2) oa -= 3*HALO2;
            int ob = (int)(koff2[kb] >> 16)     + rot; if (ob >= 3*HALO2) ob -= 3*HALO2;
            const uint2 a0 = sl[oa + xadd];
            const uint2 a1 = sl[ob + xadd];
            const bf8 af = __builtin_bit_cast(bf8, make_uint4(a0.x, a0.y, a1.x, a1.y));
            #pragma unroll
            for (int ct = 0; ct < 4; ++ct)
                acc[ct] = __builtin_amdgcn_mfma_f32_16x16x32_bf16(
                              wcf[ct][kb], af, acc[ct], 0, 0, 0);
        }
        __builtin_amdgcn_s_setprio(0);
        const size_t p = orow + tsel*16 + (size_t)t * ZYX;
        #pragma unroll
        for (int ct = 0; ct < 4; ++ct) {
            float* outp = (ct < 2) ? yr : yi;
            *reinterpret_cast<f32x4*>(outp + p*F_ + (ct & 1)*16 + lg*4) = acc[ct];
        }
    };

    // prologue: slot2 <- slice -1 (clamped 0), slot0 <- slice 0; slice 1 in flight
    STAGE_ISSUE(-1); STAGE_WRITE(2);
    STAGE_ISSUE(0);  STAGE_WRITE(0);
    STAGE_ISSUE(1);

    #pragma unroll 1
    for (int t = 0; t < T_; ++t) {
        STAGE_WRITE((t+1) % 3);             // slot now holds slice t+1
        if (t < T_-1) STAGE_ISSUE(t+2);     // issue next (clamped) slice
        const int rot = ((t+2) % 3) * HALO2; // slot(kt) = (t-1+kt) mod 3
        COMPUTE(rot, t, 0,  0);             // tile A
        COMPUTE(rot, t, 16, 1);             // tile B
    }
}

extern "C" void kernel_launch(void* const* d_in, const int* in_sizes, int n_in,
                              void* d_out, int out_size, void* d_ws, size_t ws_size,
                              hipStream_t stream)
{
    const float* xr  = (const float*)d_in[0];
    const float* xi  = (const float*)d_in[1];
    const float* wxr = (const float*)d_in[2];
    const float* wxi = (const float*)d_in[3];
    const float* wtr = (const float*)d_in[4];
    const float* wti = (const float*)d_in[5];

    float* ws   = (float*)d_ws;
    float* psr  = ws;                                    // 1728
    float* psi  = ws + 2048;                             // 1728
    float* ptr_ = ws + 4096;                             // 3072
    float* pti  = ws + 8192;                             // 3072
    unsigned short* wc = (unsigned short*)(ws + 12288);  // 22528 ushorts (45KB)
    uint2* xb          = (uint2*)(ws + 32768);           // NPTS uint2 (10.5MB)

    float* yr = (float*)d_out;
    float* yi = yr + (size_t)NPTS * F_;

    hipLaunchKernelGGL(project_kernel, dim3(64), dim3(64), 0, stream,
                       wxr, wxi, wtr, wti, psr, psi, ptr_, pti);
    hipLaunchKernelGGL(pack_comb_kernel, dim3(44), dim3(256), 0, stream,
                       psr, psi, ptr_, pti, wc);
    hipLaunchKernelGGL(repack_kernel, dim3(NPTS/256), dim3(256), 0, stream,
                       xr, xi, xb);
    hipLaunchKernelGGL(fused_kernel, dim3(B_*Z_*(Y_/2)), dim3(256), 0, stream,
                       xb, wc, yr, yi);
}

// Round 15
// 119.882 us; speedup vs baseline: 1.0076x; 1.0076x over previous
//
#include <hip/hip_runtime.h>

#define B_ 2
#define T_ 8
#define Z_ 20
#define Y_ 64
#define X_ 64
#define C_ 2
#define F1_ 32
#define F_ 32

constexpr int NPTS = B_*T_*Z_*Y_*X_;   // 1,310,720
constexpr int ZYX  = Z_*Y_*X_;         // 81,920

constexpr int HALO2   = 3*3*34;        // 306 uint2 per slice per wave
constexpr int NKB     = 11;            // K = 352 (324 real + pad)
constexpr int K_REAL  = 324;

using bf8   = __attribute__((ext_vector_type(8))) short;
using f32x4 = __attribute__((ext_vector_type(4))) float;

__device__ inline unsigned short f2bf(float x) {   // RNE float->bf16
    unsigned u = __builtin_bit_cast(unsigned, x);
    return (unsigned short)((u + 0x7fff + ((u >> 16) & 1)) >> 16);
}
__device__ inline unsigned pk(float a, float b) {  // pack 2 bf16 into dword
    return (unsigned)f2bf(a) | ((unsigned)f2bf(b) << 16);
}

// ---------------------------------------------------------------------------
// Weight projection (verified, unchanged). Outputs fp32 projected weights:
// psr/psi[(tap*2+cin)*32 + f1], ptr_/pti[(kt*32+f1)*32 + f].
// ---------------------------------------------------------------------------
__global__ __launch_bounds__(64) void project_kernel(
    const float* __restrict__ wxr, const float* __restrict__ wxi,
    const float* __restrict__ wtr, const float* __restrict__ wti,
    float* __restrict__ psr, float* __restrict__ psi,
    float* __restrict__ otr, float* __restrict__ oti)
{
    const int bid  = blockIdx.x;
    const int lane = threadIdx.x;

    if (bid < F1_) {
        const int f = bid;
        float er = 0.f, ei = 0.f;
        if (lane < 54) { er = wxr[lane*F1_ + f]; ei = wxi[lane*F1_ + f]; }
        float sr = er, si = ei;
        #pragma unroll
        for (int o = 32; o >= 1; o >>= 1) { sr += __shfl_xor(sr, o); si += __shfl_xor(si, o); }
        const float mr = sr * (1.f/54.f), mi = si * (1.f/54.f);
        const float dr = er - mr, di = ei - mi;
        float sq = (lane < 54) ? (dr*dr + di*di) : 0.f;
        #pragma unroll
        for (int o = 32; o >= 1; o >>= 1) sq += __shfl_xor(sq, o);
        const float s = 1.f / fmaxf(sqrtf(sq), 1.f);
        if (lane < 54) { psr[lane*F1_ + f] = dr*s; psi[lane*F1_ + f] = di*s; }
    } else {
        const int f = bid - F1_;
        float er[2], ei[2];
        float sq = 0.f;
        #pragma unroll
        for (int k = 0; k < 2; ++k) {
            const int e = lane + k*64;
            if (e < 96) { er[k] = wtr[e*F_ + f]; ei[k] = wti[e*F_ + f]; sq += er[k]*er[k] + ei[k]*ei[k]; }
            else        { er[k] = 0.f;  ei[k] = 0.f; }
        }
        #pragma unroll
        for (int o = 32; o >= 1; o >>= 1) sq += __shfl_xor(sq, o);
        const float s = 1.f / fmaxf(sqrtf(sq), 1.f);
        #pragma unroll
        for (int k = 0; k < 2; ++k) {
            const int e = lane + k*64;
            if (e < 96) { otr[e*F_ + f] = er[k]*s; oti[e*F_ + f] = ei[k]*s; }
        }
    }
}

// ---------------------------------------------------------------------------
// Combined-weight pack: W4[K4][n], K4 = tap4*4 + q, tap4 = kt*27+tap in
// [0,81), q = cp*2+cin; n<32 -> yr[f=n], n>=32 -> yi[f=n-32].
// W4 = f1-contraction of (spatial complex weight) x (temporal complex weight):
//   cr = sum_f1 wsr*wtr - wsi*wti ; ci = sum_f1 wsr*wti + wsi*wtr
//   W4[n<32] = cp ? -ci : cr ;  W4[n>=32] = cp ? cr : ci.
// Emitted directly in MFMA B-fragment order (layout identical to verified
// packs): wc[((ct*11+kb)*64 + l)*8 + j] = W4[kb*32+(l>>4)*8+j][ct*16+(l&15)].
// ---------------------------------------------------------------------------
__global__ __launch_bounds__(256) void pack_comb_kernel(
    const float* __restrict__ psr, const float* __restrict__ psi,
    const float* __restrict__ ptr_, const float* __restrict__ pti,
    unsigned short* __restrict__ wc)
{
    for (int o = blockIdx.x*512 + threadIdx.x; o < blockIdx.x*512 + 512; o += 256) {
        const int j  = o & 7;
        const int l  = (o >> 3) & 63;
        const int g  = o >> 9;           // ct*11 + kb
        const int kb = g % NKB, ct = g / NKB;
        const int k  = kb*32 + (l >> 4)*8 + j;
        const int n  = ct*16 + (l & 15);
        float v = 0.f;
        if (k < K_REAL) {
            const int tap4 = k >> 2, q = k & 3, cin = q & 1, cp = q >> 1;
            const int kt = tap4 / 27, tap = tap4 % 27;
            const int f  = n & 31;
            float cr = 0.f, ci = 0.f;
            const float* wsr = psr + (tap*2 + cin)*F1_;
            const float* wsi = psi + (tap*2 + cin)*F1_;
            #pragma unroll 8
            for (int f1 = 0; f1 < F1_; ++f1) {
                const float ar = wsr[f1],                    ai = wsi[f1];
                const float br = ptr_[(kt*F1_ + f1)*F_ + f], bi = pti[(kt*F1_ + f1)*F_ + f];
                cr += ar*br - ai*bi;
                ci += ar*bi + ai*br;
            }
            v = (n < 32) ? (cp ? -ci : cr) : (cp ? cr : ci);
        }
        wc[o] = f2bf(v);
    }
}

// ---------------------------------------------------------------------------
// Repack input to bf16: xb[p] = uint2{ r0|r1<<16, i0|i1<<16 }. Unchanged.
// ---------------------------------------------------------------------------
__global__ __launch_bounds__(256) void repack_kernel(
    const float* __restrict__ xr, const float* __restrict__ xi,
    uint2* __restrict__ xb)
{
    const int p = blockIdx.x*256 + threadIdx.x;
    const float2 vr = *reinterpret_cast<const float2*>(xr + (size_t)p*2);
    const float2 vi = *reinterpret_cast<const float2*>(xi + (size_t)p*2);
    uint2 v;
    v.x = (unsigned)f2bf(vr.x) | ((unsigned)f2bf(vr.y) << 16);
    v.y = (unsigned)f2bf(vi.x) | ((unsigned)f2bf(vi.y) << 16);
    xb[p] = v;
}

// ---------------------------------------------------------------------------
// Fused SINGLE-GEMM kernel: y(t) computed directly from input slices
// {t-1,t,t+1} (3-slot sliding LDS slab, one new slice staged per t) with the
// combined 352x64 weight held in 176 VGPRs. No intermediate, no ring, no
// bf16 conversion of s. Dual x-tile per wave (r10 mapping). A-fragment build,
// MFMA operand convention, and store epilogue byte-inherited from the
// verified kernels.
// ---------------------------------------------------------------------------
__global__ __launch_bounds__(256, 2) void fused_kernel(
    const uint2* __restrict__ xb,
    const unsigned short* __restrict__ wc,
    float* __restrict__ yr, float* __restrict__ yi)
{
    __shared__ uint2 slab[4][3*HALO2];       // 29.4 KB

    const int tid  = threadIdx.x;
    const int lane = tid & 63;
    const int wid  = tid >> 6;
    const int lx   = lane & 15;
    const int lg   = lane >> 4;

    const int bq    = blockIdx.x;        // b*Z*32 + z*32 + ypair
    const int ypair = bq & 31;           // Y/2 = 32
    const int z     = (bq >> 5) % Z_;
    const int b     = bq / (32*Z_);
    const int y     = ypair*2 + (wid >> 1);
    const int x0    = (wid & 1) * 32;

    // ---- combined weight fragments: 44 x 16B (176 VGPR) ----
    bf8 wcf[4][NKB];
    const bf8* w8 = reinterpret_cast<const bf8*>(wc);
    #pragma unroll
    for (int ct = 0; ct < 4; ++ct)
        #pragma unroll
        for (int kb = 0; kb < NKB; ++kb)
            wcf[ct][kb] = w8[(ct*NKB + kb)*64 + lane];

    // ---- staging offsets: 5 slots covering 306 halo points (per slice) ----
    int xoff[5];
    #pragma unroll
    for (int i = 0; i < 5; ++i) {
        int it = lane + i*64; if (it >= HALO2) it = HALO2-1;  // dup, write-guarded
        const int iz = it / 102;         // 102 = 3y*34x
        const int iy = (it / 34) % 3;
        const int ix = it % 34;
        int zz = z + iz - 1;  zz = zz < 0 ? 0 : (zz >= Z_ ? Z_-1 : zz);
        int yy = y + iy - 1;  yy = yy < 0 ? 0 : (yy >= Y_ ? Y_-1 : yy);
        int xx = x0 + ix - 1; xx = xx < 0 ? 0 : (xx >= X_ ? X_-1 : xx);
        xoff[i] = (zz*Y_ + yy)*X_ + xx;
    }

    // ---- per-lane slab offsets (incl. kt-slot base), packed 2x16b ----
    // element i = kb*2+s: tap4 = kb*8 + lg*2 + s (clamped; K4>=324 has W=0)
    unsigned koff2[NKB];
    #pragma unroll
    for (int kb = 0; kb < NKB; ++kb) {
        unsigned pair = 0;
        #pragma unroll
        for (int s = 0; s < 2; ++s) {
            int t4 = kb*8 + lg*2 + s; if (t4 > 80) t4 = 80;
            const int kt = t4/27, tap = t4 - kt*27;
            const int dz = tap/9, dyx = tap - dz*9, dy = dyx/3, dx = dyx - dy*3;
            const unsigned off = kt*HALO2 + (dz*3 + dy)*34 + dx + lx;
            pair |= off << (16*s);
        }
        koff2[kb] = pair;
    }

    uint2* sl = slab[wid];
    const size_t orow = (((size_t)b*T_)*Z_ + z)*(size_t)(Y_*X_) + (size_t)y*X_ + x0 + lx;

    uint2 stmp[5];                               // in-flight slice loads

    auto STAGE_ISSUE = [&](int tau) {            // coalesced, clamped slice
        const int tc = tau < 0 ? 0 : (tau >= T_ ? T_-1 : tau);
        const uint2* xt = xb + (size_t)(b*T_ + tc)*ZYX;
        #pragma unroll
        for (int i = 0; i < 4; ++i) stmp[i] = xt[xoff[i]];
        if (lane < HALO2 - 256) stmp[4] = xt[xoff[4]];
    };
    auto STAGE_WRITE = [&](int slot) {
        uint2* s = sl + slot*HALO2;
        #pragma unroll
        for (int i = 0; i < 4; ++i) s[lane + i*64] = stmp[i];
        if (lane < HALO2 - 256) s[lane + 256] = stmp[4];
    };

    // single GEMM for one tile: 11 kb x 4 ct MFMAs straight from the slab
    auto COMPUTE = [&](int rot, int t, int xadd, int tsel) {
        f32x4 acc[4];
        #pragma unroll
        for (int ct = 0; ct < 4; ++ct) acc[ct] = (f32x4){0.f,0.f,0.f,0.f};
        __builtin_amdgcn_s_setprio(1);
        #pragma unroll
        for (int kb = 0; kb < NKB; ++kb) {
            int oa = (int)(koff2[kb] & 0xffffu) + rot; if (oa >= 3*HALO2) oa -= 3*HALO2;
            int ob = (int)(koff2[kb] >> 16)     + rot; if (ob >= 3*HALO2) ob -= 3*HALO2;
            const uint2 a0 = sl[oa + xadd];
            const uint2 a1 = sl[ob + xadd];
            const bf8 af = __builtin_bit_cast(bf8, make_uint4(a0.x, a0.y, a1.x, a1.y));
            #pragma unroll
            for (int ct = 0; ct < 4; ++ct)
                acc[ct] = __builtin_amdgcn_mfma_f32_16x16x32_bf16(
                              wcf[ct][kb], af, acc[ct], 0, 0, 0);
        }
        __builtin_amdgcn_s_setprio(0);
        const size_t p = orow + tsel*16 + (size_t)t * ZYX;
        #pragma unroll
        for (int ct = 0; ct < 4; ++ct) {
            float* outp = (ct < 2) ? yr : yi;
            *reinterpret_cast<f32x4*>(outp + p*F_ + (ct & 1)*16 + lg*4) = acc[ct];
        }
    };

    // prologue: slot2 <- slice -1 (clamped 0), slot0 <- slice 0; slice 1 in flight
    STAGE_ISSUE(-1); STAGE_WRITE(2);
    STAGE_ISSUE(0);  STAGE_WRITE(0);
    STAGE_ISSUE(1);

    #pragma unroll 1
    for (int t = 0; t < T_; ++t) {
        STAGE_WRITE((t+1) % 3);             // slot now holds slice t+1
        if (t < T_-1) STAGE_ISSUE(t+2);     // issue next (clamped) slice
        const int rot = ((t+2) % 3) * HALO2; // slot(kt) = (t-1+kt) mod 3
        COMPUTE(rot, t, 0,  0);             // tile A
        COMPUTE(rot, t, 16, 1);             // tile B
    }
}

extern "C" void kernel_launch(void* const* d_in, const int* in_sizes, int n_in,
                              void* d_out, int out_size, void* d_ws, size_t ws_size,
                              hipStream_t stream)
{
    const float* xr  = (const float*)d_in[0];
    const float* xi  = (const float*)d_in[1];
    const float* wxr = (const float*)d_in[2];
    const float* wxi = (const float*)d_in[3];
    const float* wtr = (const float*)d_in[4];
    const float* wti = (const float*)d_in[5];

    float* ws   = (float*)d_ws;
    float* psr  = ws;                                    // 1728
    float* psi  = ws + 2048;                             // 1728
    float* ptr_ = ws + 4096;                             // 3072
    float* pti  = ws + 8192;                             // 3072
    unsigned short* wc = (unsigned short*)(ws + 12288);  // 22528 ushorts (45KB)
    uint2* xb          = (uint2*)(ws + 32768);           // NPTS uint2 (10.5MB)

    float* yr = (float*)d_out;
    float* yi = yr + (size_t)NPTS * F_;

    hipLaunchKernelGGL(project_kernel, dim3(64), dim3(64), 0, stream,
                       wxr, wxi, wtr, wti, psr, psi, ptr_, pti);
    hipLaunchKernelGGL(pack_comb_kernel, dim3(44), dim3(256), 0, stream,
                       psr, psi, ptr_, pti, wc);
    hipLaunchKernelGGL(repack_kernel, dim3(NPTS/256), dim3(256), 0, stream,
                       xr, xi, xb);
    hipLaunchKernelGGL(fused_kernel, dim3(B_*Z_*(Y_/2)), dim3(256), 0, stream,
                       xb, wc, yr, yi);
}

// Round 16
// 89.751 us; speedup vs baseline: 1.3458x; 1.3357x over previous
//
#include <hip/hip_runtime.h>

#define B_ 2
#define T_ 8
#define Z_ 20
#define Y_ 64
#define X_ 64
#define C_ 2
#define F1_ 32
#define F_ 32

constexpr int NPTS = B_*T_*Z_*Y_*X_;   // 1,310,720
constexpr int ZYX  = Z_*Y_*X_;         // 81,920

constexpr int RING_STRIDE = 36;            // dwords/row (16B-aligned rows)
constexpr int SLOT_DW     = 16*RING_STRIDE;// 576 dwords per ring slot
constexpr int HALO2       = 3*3*34;        // 306 uint2 per wave per t (32x span)
constexpr int REPACK_BLKS = NPTS/256;      // 5120

using bf8   = __attribute__((ext_vector_type(8))) short;
using f32x4 = __attribute__((ext_vector_type(4))) float;

__device__ inline unsigned short f2bf(float x) {   // RNE float->bf16
    unsigned u = __builtin_bit_cast(unsigned, x);
    return (unsigned short)((u + 0x7fff + ((u >> 16) & 1)) >> 16);
}
__device__ inline unsigned pk(float a, float b) {  // pack 2 bf16 into dword
    return (unsigned)f2bf(a) | ((unsigned)f2bf(b) << 16);
}

// ---------------------------------------------------------------------------
// prep_kernel: 5160 INDEPENDENT blocks (no stragglers).
//  - blocks [0, 5120): bf16 input repack (verified math).
//  - blocks [5120, 5136): spatial weight pack; each block redundantly
//    projects the spatial weights into LDS (verified r12 block-0 loop),
//    then packs its 512 fragment elements (verified r10 formulas).
//  - blocks [5136, 5160): temporal weight pack, same pattern.
// ---------------------------------------------------------------------------
__global__ __launch_bounds__(256) void prep_kernel(
    const float* __restrict__ wxr, const float* __restrict__ wxi,
    const float* __restrict__ wtr, const float* __restrict__ wti,
    const float* __restrict__ xr,  const float* __restrict__ xi,
    unsigned short* __restrict__ wsp, unsigned short* __restrict__ wp,
    uint2* __restrict__ xb)
{
    const int tid = threadIdx.x;

    if (blockIdx.x < REPACK_BLKS) {
        // ---- repack (verified) ----
        const int p = blockIdx.x*256 + tid;
        const float2 vr = *reinterpret_cast<const float2*>(xr + (size_t)p*2);
        const float2 vi = *reinterpret_cast<const float2*>(xi + (size_t)p*2);
        xb[p] = make_uint2(pk(vr.x, vr.y), pk(vi.x, vi.y));
        return;
    }

    __shared__ float s_a[96*F_], s_b[96*F_];
    const int lane = tid & 63;
    const int w    = tid >> 6;
    const int g2   = blockIdx.x - REPACK_BLKS;   // 0..39

    if (g2 < 16) {
        // ---- spatial: project (zero-mean + norm) into LDS, all 32 f ----
        for (int i = 0; i < 8; ++i) {
            const int f = w*8 + i;
            float er = 0.f, ei = 0.f;
            if (lane < 54) { er = wxr[lane*F1_ + f]; ei = wxi[lane*F1_ + f]; }
            float sr = er, si = ei;
            #pragma unroll
            for (int o = 32; o >= 1; o >>= 1) { sr += __shfl_xor(sr, o); si += __shfl_xor(si, o); }
            const float mr = sr * (1.f/54.f), mi = si * (1.f/54.f);
            const float dr = er - mr, di = ei - mi;
            float sq = (lane < 54) ? (dr*dr + di*di) : 0.f;
            #pragma unroll
            for (int o = 32; o >= 1; o >>= 1) sq += __shfl_xor(sq, o);
            const float s = 1.f / fmaxf(sqrtf(sq), 1.f);
            if (lane < 54) { s_a[lane*F1_ + f] = dr*s; s_b[lane*F1_ + f] = di*s; }
        }
        __syncthreads();
        // ---- pack this block's 512 spatial fragment elements (verified) ----
        for (int o = g2*512 + tid; o < g2*512 + 512; o += 256) {
            const int j  = o & 7;
            const int l  = (o >> 3) & 63;
            const int gg = o >> 9;
            const int kb = gg & 3, ct = gg >> 2;
            const int k  = kb*32 + (l >> 4)*8 + j;
            const int n  = ct*16 + (l & 15);
            float v = 0.f;
            if (k < 108) {
                const int tap = k >> 2, q = k & 3, cin = q & 1, cp = q >> 1;
                const int f  = n & 31;
                const float wr_ = s_a[(tap*2 + cin)*F1_ + f];
                const float wi_ = s_b[(tap*2 + cin)*F1_ + f];
                v = (n < 32) ? (cp ? -wi_ : wr_) : (cp ? wr_ : wi_);
            }
            wsp[o] = f2bf(v);
        }
    } else {
        // ---- temporal: project (norm only) into LDS, all 32 f ----
        for (int i = 0; i < 8; ++i) {
            const int f = w*8 + i;
            float er[2], ei[2];
            float sq = 0.f;
            #pragma unroll
            for (int k = 0; k < 2; ++k) {
                const int e = lane + k*64;
                if (e < 96) { er[k] = wtr[e*F_ + f]; ei[k] = wti[e*F_ + f]; sq += er[k]*er[k] + ei[k]*ei[k]; }
                else        { er[k] = 0.f;  ei[k] = 0.f; }
            }
            #pragma unroll
            for (int o = 32; o >= 1; o >>= 1) sq += __shfl_xor(sq, o);
            const float s = 1.f / fmaxf(sqrtf(sq), 1.f);
            #pragma unroll
            for (int k = 0; k < 2; ++k) {
                const int e = lane + k*64;
                if (e < 96) { s_a[e*F_ + f] = er[k]*s; s_b[e*F_ + f] = ei[k]*s; }
            }
        }
        __syncthreads();
        // ---- pack this block's 512 temporal fragment elements (verified) ----
        const int gt = g2 - 16;
        for (int o = gt*512 + tid; o < gt*512 + 512; o += 256) {
            const int j  = o & 7;
            const int l  = (o >> 3) & 63;
            const int gg = o >> 9;          // ct*6 + kb
            const int kb = gg % 6, ct = gg / 6;
            const int k  = kb*32 + (l >> 4)*8 + j;
            const int n  = ct*16 + (l & 15);
            const int kt = k >> 6, f1 = (k >> 1) & 31, c = k & 1;
            const int f  = n & 31;
            const float wr_ = s_a[(kt*F1_ + f1)*F_ + f];
            const float wi_ = s_b[(kt*F1_ + f1)*F_ + f];
            const float v   = (n < 32) ? (c ? -wi_ : wr_) : (c ? wr_ : wi_);
            wp[o] = f2bf(v);
        }
    }
}

// ---------------------------------------------------------------------------
// Fused kernel, DUAL X-TILE — byte-exact round-13 version (91.3 us best).
// ---------------------------------------------------------------------------
__global__ __launch_bounds__(256, 2) void fused_kernel(
    const uint2* __restrict__ xb,
    const unsigned short* __restrict__ wsp,
    const unsigned short* __restrict__ wp,
    float* __restrict__ yr, float* __restrict__ yi)
{
    __shared__ uint4 ring4[4*2*3*SLOT_DW/4];   // 55.3 KB (4 waves x 2 tiles)
    __shared__ uint2 slab[4][2][HALO2];        // 19.6 KB
    unsigned* ring = reinterpret_cast<unsigned*>(ring4);

    const int tid  = threadIdx.x;
    const int lane = tid & 63;
    const int wid  = tid >> 6;
    const int lx   = lane & 15;
    const int lg   = lane >> 4;

    const int bq    = blockIdx.x;        // b*Z*32 + z*32 + ypair
    const int ypair = bq & 31;           // Y/2 = 32
    const int z     = (bq >> 5) % Z_;
    const int b     = bq / (32*Z_);
    const int y     = ypair*2 + (wid >> 1);
    const int x0    = (wid & 1) * 32;

    // ---- weight fragments (A-operands; verified bytes) ----
    bf8 wsf[4][4];
    const bf8* w8 = reinterpret_cast<const bf8*>(wsp);
    #pragma unroll
    for (int ct = 0; ct < 4; ++ct)
        #pragma unroll
        for (int kb = 0; kb < 4; ++kb)
            wsf[ct][kb] = w8[(ct*4 + kb)*64 + lane];

    bf8 wtf[4][6];
    const bf8* wp8 = reinterpret_cast<const bf8*>(wp);
    #pragma unroll
    for (int ct = 0; ct < 4; ++ct)
        #pragma unroll
        for (int kb = 0; kb < 6; ++kb)
            wtf[ct][kb] = wp8[(ct*6 + kb)*64 + lane];

    // ---- staging offsets: 5 slots covering 306 halo points ----
    int xoff[5];
    #pragma unroll
    for (int i = 0; i < 5; ++i) {
        int it = lane + i*64; if (it >= HALO2) it = HALO2-1;  // dup, write-guarded
        const int iz = it / 102;         // 102 = 3y*34x
        const int iy = (it / 34) % 3;
        const int ix = it % 34;
        int zz = z + iz - 1;  zz = zz < 0 ? 0 : (zz >= Z_ ? Z_-1 : zz);
        int yy = y + iy - 1;  yy = yy < 0 ? 0 : (yy >= Y_ ? Y_-1 : yy);
        int xx = x0 + ix - 1; xx = xx < 0 ? 0 : (xx >= X_ ? X_-1 : xx);
        xoff[i] = (zz*Y_ + yy)*X_ + xx;
    }

    // ---- per-lane slab read offsets for the A-gather (tile A; +16 for B) ----
    int o8[4][2];
    #pragma unroll
    for (int kb = 0; kb < 4; ++kb)
        #pragma unroll
        for (int s = 0; s < 2; ++s) {
            int ta = kb*8 + lg*2 + s; if (ta > 26) ta = 26;   // k>=108: B is 0
            const int dz = ta/9, dyx = ta - dz*9, dy = dyx/3, dx = dyx - dy*3;
            o8[kb][s] = (dz*3 + dy)*34 + dx + lx;
        }

    unsigned* myring  = ring + wid*(2*3*SLOT_DW);
    const int  rbase  = lx*RING_STRIDE + lg*4;   // dword offset within a slot
    const size_t orow = (((size_t)b*T_)*Z_ + z)*(size_t)(Y_*X_) + (size_t)y*X_ + x0 + lx;

    uint4 caLo, caHi, cbLo, cbHi;                // current slices, tiles A/B
    uint2 stmp[5];                               // in-flight halo loads

    auto STAGE_ISSUE = [&](int t) {              // coalesced, issued early
        const uint2* xt = xb + (size_t)(b*T_ + t)*ZYX;
        #pragma unroll
        for (int i = 0; i < 4; ++i) stmp[i] = xt[xoff[i]];
        if (lane < HALO2 - 256) stmp[4] = xt[xoff[4]];
    };
    auto STAGE_WRITE = [&](int bufsel) {
        uint2* s = slab[wid][bufsel];
        #pragma unroll
        for (int i = 0; i < 4; ++i) s[lane + i*64] = stmp[i];
        if (lane < HALO2 - 256) s[lane + 256] = stmp[4];
    };

    // spatial MFMA for one tile: slab -> (lo,hi) in temporal-B-fragment layout
    auto SPATIAL = [&](int bufsel, int xadd, uint4& lo, uint4& hi) {
        const uint2* s = slab[wid][bufsel];
        bf8 af[4];
        #pragma unroll
        for (int kb = 0; kb < 4; ++kb) {
            const uint2 l2 = s[o8[kb][0] + xadd];
            const uint2 h2 = s[o8[kb][1] + xadd];
            af[kb] = __builtin_bit_cast(bf8, make_uint4(l2.x, l2.y, h2.x, h2.y));
        }
        f32x4 acc[4];
        #pragma unroll
        for (int ct = 0; ct < 4; ++ct) acc[ct] = (f32x4){0.f,0.f,0.f,0.f};
        __builtin_amdgcn_s_setprio(1);
        #pragma unroll
        for (int ct = 0; ct < 4; ++ct)
            #pragma unroll
            for (int kb = 0; kb < 4; ++kb)
                acc[ct] = __builtin_amdgcn_mfma_f32_16x16x32_bf16(
                              wsf[ct][kb], af[kb], acc[ct], 0, 0, 0);
        __builtin_amdgcn_s_setprio(0);
        lo = make_uint4(pk(acc[0][0],acc[2][0]), pk(acc[0][1],acc[2][1]),
                        pk(acc[0][2],acc[2][2]), pk(acc[0][3],acc[2][3]));
        hi = make_uint4(pk(acc[1][0],acc[3][0]), pk(acc[1][1],acc[3][1]),
                        pk(acc[1][2],acc[3][2]), pk(acc[1][3],acc[3][3]));
    };

    auto WRITE = [&](int tsel, int t, const uint4& lo, const uint4& hi) {
        unsigned* s = myring + tsel*(3*SLOT_DW) + (t % 3)*SLOT_DW + rbase;
        *reinterpret_cast<uint4*>(s)      = lo;
        *reinterpret_cast<uint4*>(s + 16) = hi;
    };

    // y(tout) for one tile: kt0/kt1 from ring, kt2 = cur regs
    auto EMIT = [&](int tsel, const uint4& clo, const uint4& chi,
                    int sa, int sb, int tout) {
        const unsigned* tb = myring + tsel*(3*SLOT_DW);
        const unsigned* pa = tb + (sa % 3)*SLOT_DW + rbase;
        const unsigned* pb = tb + (sb % 3)*SLOT_DW + rbase;
        bf8 fr[6];
        fr[0] = __builtin_bit_cast(bf8, *reinterpret_cast<const uint4*>(pa));
        fr[1] = __builtin_bit_cast(bf8, *reinterpret_cast<const uint4*>(pa + 16));
        fr[2] = __builtin_bit_cast(bf8, *reinterpret_cast<const uint4*>(pb));
        fr[3] = __builtin_bit_cast(bf8, *reinterpret_cast<const uint4*>(pb + 16));
        fr[4] = __builtin_bit_cast(bf8, clo);
        fr[5] = __builtin_bit_cast(bf8, chi);
        f32x4 acc[4];
        #pragma unroll
        for (int ct = 0; ct < 4; ++ct) acc[ct] = (f32x4){0.f,0.f,0.f,0.f};
        __builtin_amdgcn_s_setprio(1);
        #pragma unroll
        for (int ct = 0; ct < 4; ++ct)
            #pragma unroll
            for (int kb = 0; kb < 6; ++kb)
                acc[ct] = __builtin_amdgcn_mfma_f32_16x16x32_bf16(
                              wtf[ct][kb], fr[kb], acc[ct], 0, 0, 0);
        __builtin_amdgcn_s_setprio(0);
        const size_t p = orow + tsel*16 + (size_t)tout * ZYX;
        #pragma unroll
        for (int ct = 0; ct < 4; ++ct) {
            float* outp = (ct < 2) ? yr : yi;
            *reinterpret_cast<f32x4*>(outp + p*F_ + (ct & 1)*16 + lg*4) = acc[ct];
        }
    };

    // prologue: slab0 = t=0; t=1 loads in flight
    STAGE_ISSUE(0);
    STAGE_WRITE(0);
    STAGE_ISSUE(1);
    SPATIAL(0, 0,  caLo, caHi);
    SPATIAL(0, 16, cbLo, cbHi);
    WRITE(0, 0, caLo, caHi);
    WRITE(1, 0, cbLo, cbHi);

    #pragma unroll 1
    for (int t = 1; t < T_; ++t) {
        STAGE_WRITE(t & 1);                 // complete slab(t)
        if (t < T_-1) STAGE_ISSUE(t+1);     // issue next halo immediately
        const int sa = t-2 < 0 ? 0 : t-2;
        SPATIAL(t & 1, 0,  caLo, caHi);     // two independent MFMA chains
        SPATIAL(t & 1, 16, cbLo, cbHi);
        EMIT(0, caLo, caHi, sa, t-1, t-1);
        EMIT(1, cbLo, cbHi, sa, t-1, t-1);
        WRITE(0, t, caLo, caHi);
        WRITE(1, t, cbLo, cbHi);
    }
    EMIT(0, caLo, caHi, T_-2, T_-1, T_-1);  // y(7) = (s6, s7, s7)
    EMIT(1, cbLo, cbHi, T_-2, T_-1, T_-1);
}

extern "C" void kernel_launch(void* const* d_in, const int* in_sizes, int n_in,
                              void* d_out, int out_size, void* d_ws, size_t ws_size,
                              hipStream_t stream)
{
    const float* xr  = (const float*)d_in[0];
    const float* xi  = (const float*)d_in[1];
    const float* wxr = (const float*)d_in[2];
    const float* wxi = (const float*)d_in[3];
    const float* wtr = (const float*)d_in[4];
    const float* wti = (const float*)d_in[5];

    float* ws   = (float*)d_ws;
    unsigned short* wsp = (unsigned short*)(ws + 12288); // 8192 ushorts (16KB)
    unsigned short* wp  = (unsigned short*)(ws + 16384); // 12288 ushorts (24KB)
    uint2* xb           = (uint2*)(ws + 32768);          // NPTS uint2 (10.5MB)

    float* yr = (float*)d_out;
    float* yi = yr + (size_t)NPTS * F_;

    hipLaunchKernelGGL(prep_kernel, dim3(REPACK_BLKS + 40), dim3(256), 0, stream,
                       wxr, wxi, wtr, wti, xr, xi, wsp, wp, xb);
    hipLaunchKernelGGL(fused_kernel, dim3(B_*Z_*(Y_/2)), dim3(256), 0, stream,
                       xb, wsp, wp, yr, yi);
}